// Round 5
// baseline (203.867 us; speedup 1.0000x reference)
//
#include <hip/hip_runtime.h>

#define BOND   64
#define SITES  256
#define HALF   128
#define NBATCH 128
#define OUTD   10

// d_ws float layout:
//   P0 : [0 .. 1048576)        left-packed  [128 steps][32 g][64 j] float4
//   P1 : [1048576 .. 2097152)  right-packed (transposed, step k = site 255-k)
//   vecs: [2097152 .. 2113536) [2][128][64] propagated end vectors
#define P1_OFF   1048576
#define VEC_OFF  2097152
#define SITE_F4  2048          // float4s per packed site (64*64*2 floats)
#define LPITCH   132           // LDS transpose pitch (floats), 16B-aligned rows

typedef __attribute__((ext_vector_type(4))) float f32x4;
#define AS1 __attribute__((address_space(1)))
#define AS3 __attribute__((address_space(3)))

// ---------------------------------------------------------------------------
// Pack kernel (unchanged, R0/R3-proven): one block per site, LDS transpose,
// coalesced both ways.
//   P[step][g][j] float4 = {c0[2g][j], c1[2g][j], c0[2g+1][j], c1[2g+1][j]}
// (side 1 stores the transposed core so the chain kernel always does v^T M).
// ---------------------------------------------------------------------------
__global__ void __launch_bounds__(256)
mps_pack_kernel(const float* __restrict__ cores, float* __restrict__ P) {
  __shared__ __align__(16) float ld[64 * LPITCH];
  const int s = (int)blockIdx.x;
  const int t = (int)threadIdx.x;
  const float4* src = (const float4*)(cores + (size_t)s * 8192);
  #pragma unroll
  for (int k = 0; k < 8; ++k) {
    const int m = t + 256 * k;
    const int row = m >> 5;
    const int c4  = m & 31;
    *(float4*)&ld[row * LPITCH + c4 * 4] = src[m];
  }
  __syncthreads();
  const bool right = s >= HALF;
  const int step = right ? (SITES - 1 - s) : s;
  float4* out = (float4*)(P + (right ? P1_OFF : 0)) + (size_t)step * SITE_F4;
  #pragma unroll
  for (int k = 0; k < 8; ++k) {
    const int m = t + 256 * k;
    const int g = m >> 6;
    const int j = m & 63;
    float4 v;
    if (!right) {
      const float2 a  = *(const float2*)&ld[(2 * g) * LPITCH + 2 * j];
      const float2 b2 = *(const float2*)&ld[(2 * g + 1) * LPITCH + 2 * j];
      v = make_float4(a.x, a.y, b2.x, b2.y);
    } else {
      v = *(const float4*)&ld[j * LPITCH + 4 * g];
    }
    out[m] = v;
  }
}

// global -> LDS direct DMA, 16B per lane. LDS dest must be wave-uniform base
// (HW adds lane*16); global src is per-lane.
__device__ __forceinline__ void gload_lds16(const float* g, float* l) {
  __builtin_amdgcn_global_load_lds((const AS1 void*)g, (AS3 void*)l, 16, 0, 0);
}

// ---------------------------------------------------------------------------
// Chain kernel: 256 blocks x 64 threads. ONE WAVE = ONE FULL (batch, side)
// CHAIN (R3-proven dataflow: per-CU traffic at the 32KB/step minimum, v kept
// as lane-private r with wave-local LDS broadcast, ZERO barriers).
//
// R4's register double-buffer corrupted itself (spill reads asm buffer_load
// dests before completion + spill VMEM breaks the vmcnt count -> NaN). The
// in-flight step now lives in LDS via global_load_lds width=16 (m97/T3
// mechanism): DMA writes LDS directly, regalloc never sees the data, and the
// counted s_waitcnt vmcnt(32) waits exactly the previous step's 32 loads
// while the next step's 32 stay in flight for a full step of latency cover.
// Worst case if the compiler adds its own conservative waits: slow, never
// wrong. buf0/buf1 are distinct objects so stage(BN) and reads(BC) don't
// alias -> no spurious compiler drain between them.
// ---------------------------------------------------------------------------
__global__ void __launch_bounds__(64, 1)
mps_chain_kernel(const float* __restrict__ input,   // [128][256][2]
                 const float* __restrict__ P,       // packed cores (in ws)
                 const float* __restrict__ lvec,
                 const float* __restrict__ rvec,
                 float* __restrict__ vout) {        // ws + VEC_OFF
  __shared__ __align__(16) float buf0[8192];        // 32KB: one step's matrix
  __shared__ __align__(16) float buf1[8192];
  __shared__ __align__(16) float vbuf[BOND];        // running v broadcast slot
  __shared__ __align__(16) float xsh[HALF][2];      // x in step order

  const int lane = (int)threadIdx.x;                // 0..63
  const int side = (int)blockIdx.x & 1;             // XCD parity = side
  const int b    = (int)blockIdx.x >> 1;            // batch 0..127

  // stage x half, pre-reversed for side 1 (wave-local, DS in-order: no bar)
  {
    const float4 g =
        ((const float4*)(input + (size_t)b * SITES * 2 + side * HALF * 2))[lane];
    if (!side) {
      ((float4*)xsh)[lane] = g;                     // steps 2*lane, 2*lane+1
    } else {
      // float4 covers sites 128+2*lane (g.x,g.y), 128+2*lane+1 (g.z,g.w);
      // step = 255 - site
      ((float2*)xsh)[HALF - 1 - 2 * lane] = make_float2(g.x, g.y);
      ((float2*)xsh)[HALF - 2 - 2 * lane] = make_float2(g.z, g.w);
    }
  }

  float r = side ? rvec[lane] : lvec[lane];         // v[lane]; identity accum

  // per-lane global base: lane's 16B within each 1KB granule
  const float* gl = P + (side ? P1_OFF : 0) + lane * 4;

  // stage step STEPI (32KB = 32 granules of 1KB) into LDS buffer LDST
#define STAGEL(LDST, STEPI)                                                  \
  {                                                                          \
    const float* gs = gl + (size_t)(STEPI) * 8192;                           \
    _Pragma("unroll")                                                        \
    for (int k = 0; k < 32; ++k)                                             \
      gload_lds16(gs + k * 256, (LDST) + k * 256);                           \
  }

  STAGEL(buf0, 0);                                  // step 0 in flight

#define STEPL(BC, BN, I)                                                     \
  {                                                                          \
    /* v broadcast first: its ~120cy latency hides under stage issue */      \
    vbuf[lane] = r;                                                          \
    f32x4 vv[16];                                                            \
    _Pragma("unroll")                                                        \
    for (int k = 0; k < 16; ++k) vv[k] = ((const f32x4*)vbuf)[k];            \
    const float2 xv = *(const float2*)xsh[(I)];                              \
    const int inx = ((I) + 1 < HALF) ? (I) + 1 : (I);                        \
    STAGEL(BN, inx);                                                         \
    asm volatile("s_waitcnt vmcnt(32)" ::: "memory"); /* step I landed */    \
    __builtin_amdgcn_sched_barrier(0);                                       \
    float p0a = 0.f, p1a = 0.f, p0b = 0.f, p1b = 0.f;                        \
    _Pragma("unroll")                                                        \
    for (int q = 0; q < 16; ++q) {                                           \
      const f32x4 vq = vv[q];           /* v[4q .. 4q+3]   */                \
      const f32x4 m0 =                  /* g=2q:  l=4q,4q+1 */               \
          *(const f32x4*)&(BC)[(2 * q) * 256 + lane * 4];                    \
      const f32x4 m1 =                  /* g=2q+1:l=4q+2,4q+3 */             \
          *(const f32x4*)&(BC)[(2 * q + 1) * 256 + lane * 4];                \
      p0a = __builtin_fmaf(vq.x, m0.x, p0a);                                 \
      p1a = __builtin_fmaf(vq.x, m0.y, p1a);                                 \
      p0b = __builtin_fmaf(vq.z, m1.x, p0b);                                 \
      p1b = __builtin_fmaf(vq.z, m1.y, p1b);                                 \
      p0a = __builtin_fmaf(vq.y, m0.z, p0a);                                 \
      p1a = __builtin_fmaf(vq.y, m0.w, p1a);                                 \
      p0b = __builtin_fmaf(vq.w, m1.z, p0b);                                 \
      p1b = __builtin_fmaf(vq.w, m1.w, p1b);                                 \
    }                                                                        \
    r = __builtin_fmaf(xv.x, p0a + p0b, __builtin_fmaf(xv.y, p1a + p1b, r)); \
  }

  for (int i = 0; i < HALF; i += 2) {
    STEPL(buf0, buf1, i);
    STEPL(buf1, buf0, i + 1);
  }
#undef STEPL
#undef STAGEL

  vout[((size_t)side * NBATCH + b) * BOND + lane] = r;
}

// ---------------------------------------------------------------------------
// logits[b][o] = sum_{m,r} vL[b][m] * oc[o][m][r] * vR[b][r]
// ---------------------------------------------------------------------------
__global__ void __launch_bounds__(64)
mps_combine_kernel(const float* __restrict__ oc,    // [10][64][64]
                   const float* __restrict__ vecs,  // ws + VEC_OFF
                   float* __restrict__ out) {       // [128][10]
  __shared__ float vl[BOND];
  const int lane = (int)threadIdx.x;
  const int b = (int)blockIdx.x;
  vl[lane] = vecs[b * BOND + lane];
  const float myvr = vecs[NBATCH * BOND + b * BOND + lane];
  float res[OUTD];
  #pragma unroll
  for (int o = 0; o < OUTD; ++o) {
    float acc = 0.f;
    #pragma unroll
    for (int m = 0; m < BOND; ++m)
      acc = __builtin_fmaf(vl[m], oc[((o * BOND) + m) * BOND + lane], acc);
    acc *= myvr;
    #pragma unroll
    for (int off = 32; off > 0; off >>= 1)
      acc += __shfl_xor(acc, off, 64);
    res[o] = acc;
  }
  if (lane == 0) {
    #pragma unroll
    for (int o = 0; o < OUTD; ++o) out[b * OUTD + o] = res[o];
  }
}

extern "C" void kernel_launch(void* const* d_in, const int* in_sizes, int n_in,
                              void* d_out, int out_size, void* d_ws, size_t ws_size,
                              hipStream_t stream) {
  const float* input = (const float*)d_in[0];   // [128][256][2]
  const float* cores = (const float*)d_in[1];   // [256][64][64][2]
  const float* oc    = (const float*)d_in[2];   // [10][64][64]
  const float* lvec  = (const float*)d_in[3];   // [64]
  const float* rvec  = (const float*)d_in[4];   // [64]
  float* ws  = (float*)d_ws;
  float* out = (float*)d_out;                   // [128][10]

  hipLaunchKernelGGL(mps_pack_kernel, dim3(SITES), dim3(256), 0, stream,
                     cores, ws);
  hipLaunchKernelGGL(mps_chain_kernel, dim3(256), dim3(64), 0, stream,
                     input, ws, lvec, rvec, ws + VEC_OFF);
  hipLaunchKernelGGL(mps_combine_kernel, dim3(NBATCH), dim3(64), 0, stream,
                     oc, ws + VEC_OFF, out);
}

// Round 6
// 175.502 us; speedup vs baseline: 1.1616x; 1.1616x over previous
//
#include <hip/hip_runtime.h>

#define BOND   64
#define SITES  256
#define HALF   128
#define NBATCH 128
#define OUTD   10

// d_ws float layout:
//   P0 : [0 .. 1048576)        left-packed  [128 steps][32 g][64 j] float4
//   P1 : [1048576 .. 2097152)  right-packed (transposed, step k = site 255-k)
//   vecs: [2097152 .. 2113536) [2][128][64] propagated end vectors
#define P1_OFF   1048576
#define VEC_OFF  2097152
#define SITE_F4  2048          // float4s per packed site (64*64*2 floats)
#define LPITCH   132           // LDS transpose pitch (floats), 16B-aligned rows

typedef __attribute__((ext_vector_type(4))) float f32x4;
#define AS1 __attribute__((address_space(1)))
#define AS3 __attribute__((address_space(3)))

// ---------------------------------------------------------------------------
// Pack kernel (unchanged, proven): one block per site, LDS transpose,
// coalesced both ways.
//   P[step][g][j] float4 = {c0[2g][j], c1[2g][j], c0[2g+1][j], c1[2g+1][j]}
// (side 1 stores the transposed core so the chain kernel always does v^T M).
// ---------------------------------------------------------------------------
__global__ void __launch_bounds__(256)
mps_pack_kernel(const float* __restrict__ cores, float* __restrict__ P) {
  __shared__ __align__(16) float ld[64 * LPITCH];
  const int s = (int)blockIdx.x;
  const int t = (int)threadIdx.x;
  const float4* src = (const float4*)(cores + (size_t)s * 8192);
  #pragma unroll
  for (int k = 0; k < 8; ++k) {
    const int m = t + 256 * k;
    const int row = m >> 5;
    const int c4  = m & 31;
    *(float4*)&ld[row * LPITCH + c4 * 4] = src[m];
  }
  __syncthreads();
  const bool right = s >= HALF;
  const int step = right ? (SITES - 1 - s) : s;
  float4* out = (float4*)(P + (right ? P1_OFF : 0)) + (size_t)step * SITE_F4;
  #pragma unroll
  for (int k = 0; k < 8; ++k) {
    const int m = t + 256 * k;
    const int g = m >> 6;
    const int j = m & 63;
    float4 v;
    if (!right) {
      const float2 a  = *(const float2*)&ld[(2 * g) * LPITCH + 2 * j];
      const float2 b2 = *(const float2*)&ld[(2 * g + 1) * LPITCH + 2 * j];
      v = make_float4(a.x, a.y, b2.x, b2.y);
    } else {
      v = *(const float4*)&ld[j * LPITCH + 4 * g];
    }
    out[m] = v;
  }
}

// global -> LDS direct DMA, 16B per lane. LDS dest wave-uniform (HW adds
// lane*16); global src per-lane.
__device__ __forceinline__ void gload_lds16(const float* g, float* l) {
  __builtin_amdgcn_global_load_lds((const AS1 void*)g, (AS3 void*)l, 16, 0, 0);
}

// ---------------------------------------------------------------------------
// Chain kernel: PRODUCER-CONSUMER WAVE SPECIALIZATION.
// 128 blocks x 128 threads (2 waves). Block = (batch pair, side).
//   wave 0 (producer): per step, counted s_waitcnt vmcnt(32) -> raw s_barrier
//     -> DMA-stage step i+2 into the 3rd LDS buffer (triple buffer).
//   wave 1 (consumer): per step, raw s_barrier -> ds_read matrix + 2-batch
//     FMA wall. The consumer path contains ZERO VMEM ops, so the compiler's
//     LDS-DMA hazard tracking (which inserted the vmcnt(0) drains that made
//     R5 2436 cyc/step) has nothing to wait on in this wave: vmcnt is a
//     per-wave scoreboard. Raw s_barrier does not drain counters (HK T3/T4).
// Triple buffer safety at barrier i: consumer reads buf[i%3]; producer
// stages buf[(i+2)%3] (distinct); that buffer held step i-1, whose compute
// finished before barrier i. vmcnt(32): outstanding = steps {i, i+1} = 64
// max; waiting to 32 => step i landed (ordered completion).
// 2 batches per consumer: each LDS matrix read feeds 2 FMAs -> chip L2
// traffic halves to 512 MB; step is compute-bound: 256 fma x 2cy = 512 cyc
// ~= LDS flow 64 KB @ 128 B/cy, with DMA overlapped.
// ---------------------------------------------------------------------------
__global__ void __launch_bounds__(128, 1)
mps_chain_kernel(const float* __restrict__ input,   // [128][256][2]
                 const float* __restrict__ P,       // packed cores (in ws)
                 const float* __restrict__ lvec,
                 const float* __restrict__ rvec,
                 float* __restrict__ vout) {        // ws + VEC_OFF
  __shared__ __align__(16) float buf0[8192];        // 3 x 32KB step buffers
  __shared__ __align__(16) float buf1[8192];
  __shared__ __align__(16) float buf2[8192];
  __shared__ __align__(16) float vb0[BOND];         // batch0 running v
  __shared__ __align__(16) float vb1[BOND];         // batch1 running v
  __shared__ __align__(16) float xsh[2][HALF][2];   // per-batch x, step order

  const int t    = (int)threadIdx.x;
  const int w    = t >> 6;
  const int lane = t & 63;
  const int side = (int)blockIdx.x & 1;             // XCD parity = side
  const int pair = (int)blockIdx.x >> 1;            // 0..63
  const int b0   = 2 * pair;

#define STAGEL(LDST, STEPI)                                                  \
  {                                                                          \
    const float* gs = gl + (size_t)(STEPI) * 8192;                           \
    _Pragma("unroll")                                                        \
    for (int k = 0; k < 32; ++k)                                             \
      gload_lds16(gs + k * 256, (LDST) + k * 256);                           \
  }

  if (w == 0) {
    // ---------------- PRODUCER ----------------
    const float* gl = P + (side ? P1_OFF : 0) + lane * 4;
    float* sA = buf0;  // holds step i   at loop entry
    float* sB = buf1;  // step i+1
    float* sC = buf2;  // stage target: step i+2
    STAGEL(sA, 0);
    STAGEL(sB, 1);
    for (int i = 0; i < HALF; ++i) {
      asm volatile("s_waitcnt vmcnt(32)" ::: "memory");  // step i landed
      __builtin_amdgcn_s_barrier();                      // release step i
      const int inx = (i + 2 < HALF) ? i + 2 : HALF - 1; // clamp: uniform 32/iter
      STAGEL(sC, inx);
      float* tmp = sA; sA = sB; sB = sC; sC = tmp;
    }
  } else {
    // ---------------- CONSUMER (2 batches) ----------------
    #pragma unroll
    for (int bi = 0; bi < 2; ++bi) {
      const float4 g = ((const float4*)(input + (size_t)(b0 + bi) * SITES * 2 +
                                        side * HALF * 2))[lane];
      float* xw = &xsh[bi][0][0];
      if (!side) {
        ((float4*)xw)[lane] = g;                    // steps 2*lane, 2*lane+1
      } else {
        // sites 128+2*lane (g.x,g.y), 128+2*lane+1 (g.z,g.w); step = 255-site
        ((float2*)xw)[HALF - 1 - 2 * lane] = make_float2(g.x, g.y);
        ((float2*)xw)[HALF - 2 - 2 * lane] = make_float2(g.z, g.w);
      }
    }
    const float e = side ? rvec[lane] : lvec[lane];
    float r0 = e, r1 = e;                           // v[lane] per batch

    const float* cA = buf0;                         // step i at loop entry
    const float* cB = buf1;
    const float* cC = buf2;

    for (int i = 0; i < HALF; ++i) {
      __builtin_amdgcn_s_barrier();                 // step i ready
      vb0[lane] = r0;
      vb1[lane] = r1;
      f32x4 vv0[16], vv1[16];
      #pragma unroll
      for (int k = 0; k < 16; ++k) {
        vv0[k] = ((const f32x4*)vb0)[k];            // broadcast reads:
        vv1[k] = ((const f32x4*)vb1)[k];            // same-addr, conflict-free
      }
      const float2 x0 = *(const float2*)xsh[0][i];
      const float2 x1 = *(const float2*)xsh[1][i];
      float q0a = 0.f, q0b = 0.f, q1a = 0.f, q1b = 0.f;   // batch0 f0/f1
      float s0a = 0.f, s0b = 0.f, s1a = 0.f, s1b = 0.f;   // batch1 f0/f1
      #pragma unroll
      for (int q = 0; q < 16; ++q) {
        const f32x4 m0 = *(const f32x4*)&cA[(2 * q) * 256 + lane * 4];
        const f32x4 m1 = *(const f32x4*)&cA[(2 * q + 1) * 256 + lane * 4];
        const f32x4 u0 = vv0[q];
        const f32x4 u1 = vv1[q];
        q0a = __builtin_fmaf(u0.x, m0.x, q0a);  // l=4q   feat0
        q1a = __builtin_fmaf(u0.x, m0.y, q1a);  //        feat1
        s0a = __builtin_fmaf(u1.x, m0.x, s0a);
        s1a = __builtin_fmaf(u1.x, m0.y, s1a);
        q0a = __builtin_fmaf(u0.y, m0.z, q0a);  // l=4q+1
        q1a = __builtin_fmaf(u0.y, m0.w, q1a);
        s0a = __builtin_fmaf(u1.y, m0.z, s0a);
        s1a = __builtin_fmaf(u1.y, m0.w, s1a);
        q0b = __builtin_fmaf(u0.z, m1.x, q0b);  // l=4q+2
        q1b = __builtin_fmaf(u0.z, m1.y, q1b);
        s0b = __builtin_fmaf(u1.z, m1.x, s0b);
        s1b = __builtin_fmaf(u1.z, m1.y, s1b);
        q0b = __builtin_fmaf(u0.w, m1.z, q0b);  // l=4q+3
        q1b = __builtin_fmaf(u0.w, m1.w, q1b);
        s0b = __builtin_fmaf(u1.w, m1.z, s0b);
        s1b = __builtin_fmaf(u1.w, m1.w, s1b);
      }
      r0 = __builtin_fmaf(x0.x, q0a + q0b,
           __builtin_fmaf(x0.y, q1a + q1b, r0));
      r1 = __builtin_fmaf(x1.x, s0a + s0b,
           __builtin_fmaf(x1.y, s1a + s1b, r1));
      const float* tmp = cA; cA = cB; cB = cC; cC = tmp;
    }

    vout[((size_t)side * NBATCH + b0) * BOND + lane] = r0;
    vout[((size_t)side * NBATCH + b0 + 1) * BOND + lane] = r1;
  }
#undef STAGEL
}

// ---------------------------------------------------------------------------
// logits[b][o] = sum_{m,r} vL[b][m] * oc[o][m][r] * vR[b][r]
// ---------------------------------------------------------------------------
__global__ void __launch_bounds__(64)
mps_combine_kernel(const float* __restrict__ oc,    // [10][64][64]
                   const float* __restrict__ vecs,  // ws + VEC_OFF
                   float* __restrict__ out) {       // [128][10]
  __shared__ float vl[BOND];
  const int lane = (int)threadIdx.x;
  const int b = (int)blockIdx.x;
  vl[lane] = vecs[b * BOND + lane];
  const float myvr = vecs[NBATCH * BOND + b * BOND + lane];
  float res[OUTD];
  #pragma unroll
  for (int o = 0; o < OUTD; ++o) {
    float acc = 0.f;
    #pragma unroll
    for (int m = 0; m < BOND; ++m)
      acc = __builtin_fmaf(vl[m], oc[((o * BOND) + m) * BOND + lane], acc);
    acc *= myvr;
    #pragma unroll
    for (int off = 32; off > 0; off >>= 1)
      acc += __shfl_xor(acc, off, 64);
    res[o] = acc;
  }
  if (lane == 0) {
    #pragma unroll
    for (int o = 0; o < OUTD; ++o) out[b * OUTD + o] = res[o];
  }
}

extern "C" void kernel_launch(void* const* d_in, const int* in_sizes, int n_in,
                              void* d_out, int out_size, void* d_ws, size_t ws_size,
                              hipStream_t stream) {
  const float* input = (const float*)d_in[0];   // [128][256][2]
  const float* cores = (const float*)d_in[1];   // [256][64][64][2]
  const float* oc    = (const float*)d_in[2];   // [10][64][64]
  const float* lvec  = (const float*)d_in[3];   // [64]
  const float* rvec  = (const float*)d_in[4];   // [64]
  float* ws  = (float*)d_ws;
  float* out = (float*)d_out;                   // [128][10]

  hipLaunchKernelGGL(mps_pack_kernel, dim3(SITES), dim3(256), 0, stream,
                     cores, ws);
  hipLaunchKernelGGL(mps_chain_kernel, dim3(NBATCH), dim3(128), 0, stream,
                     input, ws, lvec, rvec, ws + VEC_OFF);
  hipLaunchKernelGGL(mps_combine_kernel, dim3(NBATCH), dim3(64), 0, stream,
                     oc, ws + VEC_OFF, out);
}

// Round 7
// 147.248 us; speedup vs baseline: 1.3845x; 1.1919x over previous
//
#include <hip/hip_runtime.h>

#define BOND   64
#define SITES  256
#define HALF   128
#define NBATCH 128
#define OUTD   10

// d_ws float layout:
//   P0 : [0 .. 1048576)        left-packed  [128 steps][32 g][64 j] float4
//   P1 : [1048576 .. 2097152)  right-packed (transposed, step k = site 255-k)
//   vecs: [2097152 .. 2113536) [2][128][64] propagated end vectors
#define P1_OFF   1048576
#define VEC_OFF  2097152
#define SITE_F4  2048          // float4s per packed site (64*64*2 floats)
#define LPITCH   132           // LDS transpose pitch (floats), 16B-aligned rows

typedef __attribute__((ext_vector_type(4))) float f32x4;
#define AS1 __attribute__((address_space(1)))
#define AS3 __attribute__((address_space(3)))

// ---------------------------------------------------------------------------
// Pack kernel (unchanged, proven): one block per site, LDS transpose,
// coalesced both ways.
//   P[step][g][j] float4 = {c0[2g][j], c1[2g][j], c0[2g+1][j], c1[2g+1][j]}
// (side 1 stores the transposed core so the chain kernel always does v^T M).
// ---------------------------------------------------------------------------
__global__ void __launch_bounds__(256)
mps_pack_kernel(const float* __restrict__ cores, float* __restrict__ P) {
  __shared__ __align__(16) float ld[64 * LPITCH];
  const int s = (int)blockIdx.x;
  const int t = (int)threadIdx.x;
  const float4* src = (const float4*)(cores + (size_t)s * 8192);
  #pragma unroll
  for (int k = 0; k < 8; ++k) {
    const int m = t + 256 * k;
    const int row = m >> 5;
    const int c4  = m & 31;
    *(float4*)&ld[row * LPITCH + c4 * 4] = src[m];
  }
  __syncthreads();
  const bool right = s >= HALF;
  const int step = right ? (SITES - 1 - s) : s;
  float4* out = (float4*)(P + (right ? P1_OFF : 0)) + (size_t)step * SITE_F4;
  #pragma unroll
  for (int k = 0; k < 8; ++k) {
    const int m = t + 256 * k;
    const int g = m >> 6;
    const int j = m & 63;
    float4 v;
    if (!right) {
      const float2 a  = *(const float2*)&ld[(2 * g) * LPITCH + 2 * j];
      const float2 b2 = *(const float2*)&ld[(2 * g + 1) * LPITCH + 2 * j];
      v = make_float4(a.x, a.y, b2.x, b2.y);
    } else {
      v = *(const float4*)&ld[j * LPITCH + 4 * g];
    }
    out[m] = v;
  }
}

// global -> LDS direct DMA, 16B per lane. LDS dest wave-uniform (HW adds
// lane*16); global src per-lane.
__device__ __forceinline__ void gload_lds16(const float* g, float* l) {
  __builtin_amdgcn_global_load_lds((const AS1 void*)g, (AS3 void*)l, 16, 0, 0);
}

// ---------------------------------------------------------------------------
// Chain kernel: producer-consumer, COLUMN-SPLIT consumers.
// 128 blocks x 192 threads (3 waves). Block = (batch pair, side).
//   wave 0 (producer): R6-proven: counted s_waitcnt vmcnt(32) -> raw
//     s_barrier -> DMA-stage step i+2 (triple buffer). Raw barrier never
//     drains vmcnt, so 64 DMAs stay pipelined.
//   waves 1,2 (consumers): wave wc owns output columns [32wc, 32wc+32);
//     lane = 2*(j-32wc) + batchslot. Each lane propagates r = v_b[j] in a
//     register across all 128 steps (no cross-wave reduce, ever). Adjacent
//     lane pairs read the SAME matrix address (broadcast-paired) -> each
//     wave moves only 16KB distinct matrix data; FMA issue halves to 256
//     cyc/wave on separate SIMDs. R6's single consumer was issue+LDS-pipe
//     serialized at ~1900 cyc/step.
//   v is cross-wave now: consumers use __syncthreads() for the step barrier
//     (its vmcnt(0) is free -- consumer path has no steady-state VMEM; its
//     lgkmcnt(0)+compiler fence orders the v-writes). Producer keeps the
//     raw barrier. Both execute exactly 128 s_barriers.
// Triple buffer: consumer reads buf[i%3]; producer stages buf[(i+2)%3].
// ---------------------------------------------------------------------------
__global__ void __launch_bounds__(192, 1)
mps_chain_kernel(const float* __restrict__ input,   // [128][256][2]
                 const float* __restrict__ P,       // packed cores (in ws)
                 const float* __restrict__ lvec,
                 const float* __restrict__ rvec,
                 float* __restrict__ vout) {        // ws + VEC_OFF
  __shared__ __align__(16) float buf0[8192];        // 3 x 32KB step buffers
  __shared__ __align__(16) float buf1[8192];
  __shared__ __align__(16) float buf2[8192];
  __shared__ __align__(16) float vb[2][68];         // per-batch running v (+pad)
  __shared__ __align__(16) float xsh[2][HALF][2];   // per-batch x, step order

  const int t    = (int)threadIdx.x;
  const int side = (int)blockIdx.x & 1;             // XCD parity = side
  const int pair = (int)blockIdx.x >> 1;            // 0..63
  const int b0   = 2 * pair;

  if (t < 64) {
    // ---------------- PRODUCER (wave 0) ----------------
    const int lane = t;
    const float* gl = P + (side ? P1_OFF : 0) + lane * 4;
    float* sA = buf0;  // step i at loop entry
    float* sB = buf1;  // step i+1
    float* sC = buf2;  // stage target: step i+2
#define STAGEL(LDST, STEPI)                                                  \
    {                                                                        \
      const float* gs = gl + (size_t)(STEPI) * 8192;                         \
      _Pragma("unroll")                                                      \
      for (int k = 0; k < 32; ++k)                                           \
        gload_lds16(gs + k * 256, (LDST) + k * 256);                         \
    }
    STAGEL(sA, 0);
    STAGEL(sB, 1);
    for (int i = 0; i < HALF; ++i) {
      asm volatile("s_waitcnt vmcnt(32)" ::: "memory");  // step i landed
      __builtin_amdgcn_s_barrier();                      // release step i
      const int inx = (i + 2 < HALF) ? i + 2 : HALF - 1; // uniform 32/iter
      STAGEL(sC, inx);
      float* tmp = sA; sA = sB; sB = sC; sC = tmp;
    }
#undef STAGEL
  } else {
    // ---------------- CONSUMERS (waves 1,2) ----------------
    const int tc   = t - 64;                        // 0..127
    const int wc   = tc >> 6;                       // column-half 0/1
    const int lane = tc & 63;
    const int jcol = (lane >> 1) + 32 * wc;         // this lane's output col
    const int bs   = lane & 1;                      // this lane's batch slot

    if (wc == 0) {
      // one-time x staging (both batches), pre-reversed for side 1
      #pragma unroll
      for (int bi = 0; bi < 2; ++bi) {
        const float4 g = ((const float4*)(input + (size_t)(b0 + bi) * SITES * 2 +
                                          side * HALF * 2))[lane];
        float* xw = &xsh[bi][0][0];
        if (!side) {
          ((float4*)xw)[lane] = g;                  // steps 2*lane, 2*lane+1
        } else {
          // sites 128+2*lane (g.x,g.y), 128+2*lane+1 (g.z,g.w); step=255-site
          ((float2*)xw)[HALF - 1 - 2 * lane] = make_float2(g.x, g.y);
          ((float2*)xw)[HALF - 2 - 2 * lane] = make_float2(g.z, g.w);
        }
      }
    }

    float r = side ? rvec[jcol] : lvec[jcol];       // v_b[jcol], identity accum
    vb[bs][jcol] = r;

    const float* cA = buf0;                         // step i at loop entry
    const float* cB = buf1;
    const float* cC = buf2;
    const float* vbp = vb[bs];                      // per-lane v base
    const float* xp  = &xsh[bs][0][0];              // per-lane x base

    for (int i = 0; i < HALF; ++i) {
      __syncthreads();                              // step i ready + v visible
      f32x4 vv[16];
      #pragma unroll
      for (int k = 0; k < 16; ++k)
        vv[k] = ((const f32x4*)vbp)[k];             // 2-addr broadcast reads
      const float2 xv = *(const float2*)&xp[2 * i];
      float p0a = 0.f, p0b = 0.f, p1a = 0.f, p1b = 0.f;
      #pragma unroll
      for (int q = 0; q < 16; ++q) {
        const f32x4 u  = vv[q];                     // v[4q .. 4q+3]
        const f32x4 mA = *(const f32x4*)&cA[(2 * q) * 256 + jcol * 4];
        const f32x4 mB = *(const f32x4*)&cA[(2 * q + 1) * 256 + jcol * 4];
        p0a = __builtin_fmaf(u.x, mA.x, p0a);       // l=4q    feat0
        p1a = __builtin_fmaf(u.x, mA.y, p1a);       //         feat1
        p0b = __builtin_fmaf(u.y, mA.z, p0b);       // l=4q+1
        p1b = __builtin_fmaf(u.y, mA.w, p1b);
        p0a = __builtin_fmaf(u.z, mB.x, p0a);       // l=4q+2
        p1a = __builtin_fmaf(u.z, mB.y, p1a);
        p0b = __builtin_fmaf(u.w, mB.z, p0b);       // l=4q+3
        p1b = __builtin_fmaf(u.w, mB.w, p1b);
      }
      r = __builtin_fmaf(xv.x, p0a + p0b,
          __builtin_fmaf(xv.y, p1a + p1b, r));
      vb[bs][jcol] = r;                             // visible after next barrier
      const float* tmp = cA; cA = cB; cB = cC; cC = tmp;
    }

    vout[((size_t)side * NBATCH + b0 + bs) * BOND + jcol] = r;
  }
}

// ---------------------------------------------------------------------------
// logits[b][o] = sum_{m,r} vL[b][m] * oc[o][m][r] * vR[b][r]
// ---------------------------------------------------------------------------
__global__ void __launch_bounds__(64)
mps_combine_kernel(const float* __restrict__ oc,    // [10][64][64]
                   const float* __restrict__ vecs,  // ws + VEC_OFF
                   float* __restrict__ out) {       // [128][10]
  __shared__ float vl[BOND];
  const int lane = (int)threadIdx.x;
  const int b = (int)blockIdx.x;
  vl[lane] = vecs[b * BOND + lane];
  const float myvr = vecs[NBATCH * BOND + b * BOND + lane];
  float res[OUTD];
  #pragma unroll
  for (int o = 0; o < OUTD; ++o) {
    float acc = 0.f;
    #pragma unroll
    for (int m = 0; m < BOND; ++m)
      acc = __builtin_fmaf(vl[m], oc[((o * BOND) + m) * BOND + lane], acc);
    acc *= myvr;
    #pragma unroll
    for (int off = 32; off > 0; off >>= 1)
      acc += __shfl_xor(acc, off, 64);
    res[o] = acc;
  }
  if (lane == 0) {
    #pragma unroll
    for (int o = 0; o < OUTD; ++o) out[b * OUTD + o] = res[o];
  }
}

extern "C" void kernel_launch(void* const* d_in, const int* in_sizes, int n_in,
                              void* d_out, int out_size, void* d_ws, size_t ws_size,
                              hipStream_t stream) {
  const float* input = (const float*)d_in[0];   // [128][256][2]
  const float* cores = (const float*)d_in[1];   // [256][64][64][2]
  const float* oc    = (const float*)d_in[2];   // [10][64][64]
  const float* lvec  = (const float*)d_in[3];   // [64]
  const float* rvec  = (const float*)d_in[4];   // [64]
  float* ws  = (float*)d_ws;
  float* out = (float*)d_out;                   // [128][10]

  hipLaunchKernelGGL(mps_pack_kernel, dim3(SITES), dim3(256), 0, stream,
                     cores, ws);
  hipLaunchKernelGGL(mps_chain_kernel, dim3(NBATCH), dim3(192), 0, stream,
                     input, ws, lvec, rvec, ws + VEC_OFF);
  hipLaunchKernelGGL(mps_combine_kernel, dim3(NBATCH), dim3(64), 0, stream,
                     oc, ws + VEC_OFF, out);
}

// Round 8
// 140.185 us; speedup vs baseline: 1.4543x; 1.0504x over previous
//
#include <hip/hip_runtime.h>

#define BOND   64
#define SITES  256
#define HALF   128
#define NBATCH 128
#define OUTD   10

// d_ws float layout:
//   P0 : [0 .. 1048576)        left-packed  [128 steps][32 g][64 j] float4
//   P1 : [1048576 .. 2097152)  right-packed (transposed, step k = site 255-k)
//   vecs: [2097152 .. 2113536) [2][128][64] propagated end vectors
#define P1_OFF   1048576
#define VEC_OFF  2097152
#define SITE_F4  2048          // float4s per packed site (64*64*2 floats)
#define LPITCH   132           // LDS transpose pitch (floats), 16B-aligned rows

typedef __attribute__((ext_vector_type(4))) float f32x4;
#define AS1 __attribute__((address_space(1)))
#define AS3 __attribute__((address_space(3)))

// ---------------------------------------------------------------------------
// Pack kernel (unchanged, proven): one block per site, LDS transpose,
// coalesced both ways.
//   P[step][g][j] float4 = {c0[2g][j], c1[2g][j], c0[2g+1][j], c1[2g+1][j]}
// (side 1 stores the transposed core so the chain kernel always does v^T M).
// ---------------------------------------------------------------------------
__global__ void __launch_bounds__(256)
mps_pack_kernel(const float* __restrict__ cores, float* __restrict__ P) {
  __shared__ __align__(16) float ld[64 * LPITCH];
  const int s = (int)blockIdx.x;
  const int t = (int)threadIdx.x;
  const float4* src = (const float4*)(cores + (size_t)s * 8192);
  #pragma unroll
  for (int k = 0; k < 8; ++k) {
    const int m = t + 256 * k;
    const int row = m >> 5;
    const int c4  = m & 31;
    *(float4*)&ld[row * LPITCH + c4 * 4] = src[m];
  }
  __syncthreads();
  const bool right = s >= HALF;
  const int step = right ? (SITES - 1 - s) : s;
  float4* out = (float4*)(P + (right ? P1_OFF : 0)) + (size_t)step * SITE_F4;
  #pragma unroll
  for (int k = 0; k < 8; ++k) {
    const int m = t + 256 * k;
    const int g = m >> 6;
    const int j = m & 63;
    float4 v;
    if (!right) {
      const float2 a  = *(const float2*)&ld[(2 * g) * LPITCH + 2 * j];
      const float2 b2 = *(const float2*)&ld[(2 * g + 1) * LPITCH + 2 * j];
      v = make_float4(a.x, a.y, b2.x, b2.y);
    } else {
      v = *(const float4*)&ld[j * LPITCH + 4 * g];
    }
    out[m] = v;
  }
}

// global -> LDS direct DMA, 16B per lane. LDS dest wave-uniform (HW adds
// lane*16); global src per-lane.
__device__ __forceinline__ void gload_lds16(const float* g, float* l) {
  __builtin_amdgcn_global_load_lds((const AS1 void*)g, (AS3 void*)l, 16, 0, 0);
}

// ---------------------------------------------------------------------------
// Chain kernel: producer + 4 L-SPLIT consumers.
// 128 blocks x 320 threads (5 waves). Block = (batch pair, side).
//   wave 0 (producer): R6/R7-proven: counted s_waitcnt vmcnt(32) -> raw
//     s_barrier -> DMA-stage step i+2 (triple buffer). Never drains vmcnt.
//   waves 1..4 (consumers): unit = (jcol, batch); partner lanes l and l^32
//     in the SAME wave take l-halves [0,32)/[32,64), so the reduce is ONE
//     __shfl_xor(t,32) -- no LDS reduce, no extra barrier.
//       wc = wave-1: jcol = (lane&31)+32*(wc&1), bs = wc>>1, lhalf = lane>>5.
//     Per wave per step: 16 matrix ds_read_b128 + 8 vv reads + 1 write = 25
//     DS instr (~300 cyc) vs R7's 48 (~580): the per-wave DS ISSUE stream
//     was R7's critical path (m134: ~12cyc/b128 per wave, issue-side).
//   vb is parity double-buffered: read vbx[i&1], write vbx[(i+1)&1] --
//     closes R7's latent same-step write/read race.
// Triple buffer: consumer reads buf[i%3]; producer stages buf[(i+2)%3].
// Step floor: per-CU L2 delivery of 32KB ~ 585 cyc at ~56 B/cyc/CU.
// ---------------------------------------------------------------------------
__global__ void __launch_bounds__(320, 1)
mps_chain_kernel(const float* __restrict__ input,   // [128][256][2]
                 const float* __restrict__ P,       // packed cores (in ws)
                 const float* __restrict__ lvec,
                 const float* __restrict__ rvec,
                 float* __restrict__ vout) {        // ws + VEC_OFF
  __shared__ __align__(16) float buf0[8192];        // 3 x 32KB step buffers
  __shared__ __align__(16) float buf1[8192];
  __shared__ __align__(16) float buf2[8192];
  __shared__ __align__(16) float vbx[2][2][68];     // [parity][batch][v +pad]
  __shared__ __align__(16) float xsh[2][HALF][2];   // per-batch x, step order

  const int t    = (int)threadIdx.x;
  const int side = (int)blockIdx.x & 1;             // XCD parity = side
  const int pair = (int)blockIdx.x >> 1;            // 0..63
  const int b0   = 2 * pair;

  if (t < 64) {
    // ---------------- PRODUCER (wave 0) ----------------
    const int lane = t;
    const float* gl = P + (side ? P1_OFF : 0) + lane * 4;
    float* sA = buf0;  // step i at loop entry
    float* sB = buf1;  // step i+1
    float* sC = buf2;  // stage target: step i+2
#define STAGEL(LDST, STEPI)                                                  \
    {                                                                        \
      const float* gs = gl + (size_t)(STEPI) * 8192;                         \
      _Pragma("unroll")                                                      \
      for (int k = 0; k < 32; ++k)                                           \
        gload_lds16(gs + k * 256, (LDST) + k * 256);                         \
    }
    STAGEL(sA, 0);
    STAGEL(sB, 1);
    for (int i = 0; i < HALF; ++i) {
      asm volatile("s_waitcnt vmcnt(32)" ::: "memory");  // step i landed
      __builtin_amdgcn_s_barrier();                      // release step i
      const int inx = (i + 2 < HALF) ? i + 2 : HALF - 1; // uniform 32/iter
      STAGEL(sC, inx);
      float* tmp = sA; sA = sB; sB = sC; sC = tmp;
    }
#undef STAGEL
  } else {
    // ---------------- CONSUMERS (waves 1..4) ----------------
    const int tc    = t - 64;                       // 0..255
    const int wc    = tc >> 6;                      // 0..3
    const int lane  = tc & 63;
    const int jcol  = (lane & 31) + 32 * (wc & 1);  // output column
    const int bs    = wc >> 1;                      // batch slot
    const int lhalf = lane >> 5;                    // l-range half

    if (wc == 0) {
      // one-time x staging (both batches), pre-reversed for side 1
      #pragma unroll
      for (int bi = 0; bi < 2; ++bi) {
        const float4 g = ((const float4*)(input + (size_t)(b0 + bi) * SITES * 2 +
                                          side * HALF * 2))[lane];
        float* xw = &xsh[bi][0][0];
        if (!side) {
          ((float4*)xw)[lane] = g;                  // steps 2*lane, 2*lane+1
        } else {
          // sites 128+2*lane (g.x,g.y), 128+2*lane+1 (g.z,g.w); step=255-site
          ((float2*)xw)[HALF - 1 - 2 * lane] = make_float2(g.x, g.y);
          ((float2*)xw)[HALF - 2 - 2 * lane] = make_float2(g.z, g.w);
        }
      }
    }

    float r = side ? rvec[jcol] : lvec[jcol];       // v[jcol], identity accum
    vbx[0][bs][jcol] = r;                           // read at step 0

    const float* cA = buf0;                         // step i at loop entry
    const float* cB = buf1;
    const float* cC = buf2;
    const float* xp = &xsh[bs][0][0];

    for (int i = 0; i < HALF; ++i) {
      __syncthreads();                              // step i data + v ready
      const float* vr = &vbx[i & 1][bs][32 * lhalf];
      f32x4 vv[8];
      #pragma unroll
      for (int k = 0; k < 8; ++k)
        vv[k] = ((const f32x4*)vr)[k];              // v[32*lhalf .. +32)
      const float2 xv = *(const float2*)&xp[2 * i];
      float p0 = 0.f, p1 = 0.f;
      #pragma unroll
      for (int q = 0; q < 16; ++q) {                // g = 16*lhalf + q
        const f32x4 m = *(const f32x4*)&cA[(16 * lhalf + q) * 256 + jcol * 4];
        const f32x4 u = vv[q >> 1];
        const float va = (q & 1) ? u.z : u.x;       // v[2g]
        const float vb2 = (q & 1) ? u.w : u.y;      // v[2g+1]
        p0 = __builtin_fmaf(va, m.x, p0);           // feat0
        p1 = __builtin_fmaf(va, m.y, p1);           // feat1
        p0 = __builtin_fmaf(vb2, m.z, p0);
        p1 = __builtin_fmaf(vb2, m.w, p1);
      }
      float tsum = __builtin_fmaf(xv.x, p0, xv.y * p1);
      tsum += __shfl_xor(tsum, 32, 64);             // partner l-half
      r += tsum;
      vbx[(i + 1) & 1][bs][jcol] = r;               // next step's v
      const float* tmp = cA; cA = cB; cB = cC; cC = tmp;
    }

    if (lhalf == 0)
      vout[((size_t)side * NBATCH + b0 + bs) * BOND + jcol] = r;
  }
}

// ---------------------------------------------------------------------------
// logits[b][o] = sum_{m,r} vL[b][m] * oc[o][m][r] * vR[b][r]
// ---------------------------------------------------------------------------
__global__ void __launch_bounds__(64)
mps_combine_kernel(const float* __restrict__ oc,    // [10][64][64]
                   const float* __restrict__ vecs,  // ws + VEC_OFF
                   float* __restrict__ out) {       // [128][10]
  __shared__ float vl[BOND];
  const int lane = (int)threadIdx.x;
  const int b = (int)blockIdx.x;
  vl[lane] = vecs[b * BOND + lane];
  const float myvr = vecs[NBATCH * BOND + b * BOND + lane];
  float res[OUTD];
  #pragma unroll
  for (int o = 0; o < OUTD; ++o) {
    float acc = 0.f;
    #pragma unroll
    for (int m = 0; m < BOND; ++m)
      acc = __builtin_fmaf(vl[m], oc[((o * BOND) + m) * BOND + lane], acc);
    acc *= myvr;
    #pragma unroll
    for (int off = 32; off > 0; off >>= 1)
      acc += __shfl_xor(acc, off, 64);
    res[o] = acc;
  }
  if (lane == 0) {
    #pragma unroll
    for (int o = 0; o < OUTD; ++o) out[b * OUTD + o] = res[o];
  }
}

extern "C" void kernel_launch(void* const* d_in, const int* in_sizes, int n_in,
                              void* d_out, int out_size, void* d_ws, size_t ws_size,
                              hipStream_t stream) {
  const float* input = (const float*)d_in[0];   // [128][256][2]
  const float* cores = (const float*)d_in[1];   // [256][64][64][2]
  const float* oc    = (const float*)d_in[2];   // [10][64][64]
  const float* lvec  = (const float*)d_in[3];   // [64]
  const float* rvec  = (const float*)d_in[4];   // [64]
  float* ws  = (float*)d_ws;
  float* out = (float*)d_out;                   // [128][10]

  hipLaunchKernelGGL(mps_pack_kernel, dim3(SITES), dim3(256), 0, stream,
                     cores, ws);
  hipLaunchKernelGGL(mps_chain_kernel, dim3(NBATCH), dim3(320), 0, stream,
                     input, ws, lvec, rvec, ws + VEC_OFF);
  hipLaunchKernelGGL(mps_combine_kernel, dim3(NBATCH), dim3(64), 0, stream,
                     oc, ws + VEC_OFF, out);
}